// Round 10
// baseline (265.984 us; speedup 1.0000x reference)
//
#include <hip/hip_runtime.h>
#include <hip/hip_bf16.h>

#define EMB 768
#define NH 8
#define DH 96
#define BATCH 8
#define SEQ 1024
#define M_TOT (BATCH * SEQ)   // 8192 rows of x
#define NCOLS (3 * EMB)       // q(768) | k(768) | v(768) output channels

typedef float f32x4 __attribute__((ext_vector_type(4)));
typedef __bf16 bf16x8 __attribute__((ext_vector_type(8)));

__device__ __forceinline__ unsigned short f2bf_bits(float f) {
  __hip_bfloat16 b = __float2bfloat16(f);
  return *reinterpret_cast<unsigned short*>(&b);
}

__device__ __forceinline__ void gload_lds16(const void* g, void* l) {
  // async global->LDS, 16B per lane; LDS dest is wave-uniform base (+lane*16 by HW)
  __builtin_amdgcn_global_load_lds(
      (__attribute__((address_space(1))) void*)(g),
      (__attribute__((address_space(3))) void*)(l), 16, 0, 0);
}

// ---------------- prep: x fp32 -> bf16 ----------------
__global__ void prep_x_kernel(const float* __restrict__ x, __hip_bfloat16* __restrict__ xb) {
  const int n4 = M_TOT * EMB / 4;
  int i = blockIdx.x * blockDim.x + threadIdx.x;
  if (i < n4) {
    f32x4 v = reinterpret_cast<const f32x4*>(x)[i];
    ushort4 o;
    o.x = f2bf_bits(v[0]);
    o.y = f2bf_bits(v[1]);
    o.z = f2bf_bits(v[2]);
    o.w = f2bf_bits(v[3]);
    reinterpret_cast<ushort4*>(xb)[i] = o;
  }
}

// ---------------- prep: permuted weights -> bf16, bias fp32 ----------------
__global__ void prep_w_kernel(const float* __restrict__ qkv_w, const float* __restrict__ qkv_b,
                              const float* __restrict__ val_w, const float* __restrict__ val_b,
                              __hip_bfloat16* __restrict__ Wall, float* __restrict__ bias) {
  const float inv_s = 0.03608439182435161f;  // 1/sqrt(768)
  int idx = blockIdx.x * 256 + threadIdx.x;
  if (idx >= NCOLS * EMB) return;
  int r = idx / EMB;
  int c = idx - r * EMB;
  float v;
  if (r < EMB) {
    int h = r / DH, d = r - h * DH;
    int src = h * 192 + 2 * d;
    v = qkv_w[(size_t)src * EMB + c] * inv_s;
    if (c == 0) bias[r] = qkv_b[src] * inv_s;
  } else if (r < 2 * EMB) {
    int r2 = r - EMB;
    int h = r2 / DH, d = r2 - h * DH;
    int src = h * 192 + 2 * d + 1;
    v = qkv_w[(size_t)src * EMB + c];
    if (c == 0) bias[r] = qkv_b[src];
  } else {
    int r3 = r - 2 * EMB;
    v = val_w[(size_t)r3 * EMB + c];
    if (c == 0) bias[r] = val_b[r3];
  }
  Wall[idx] = __float2bfloat16(v);
}

// ---------------- fused projection GEMM (m97-structure, 128x128, BK=32) ----------------
// q/k tiles: acc -> LDS (bf16) -> cooperative coalesced store into head-packed
// [b][h][n][96] layout. v tile: direct fp32 stores.  (byte-identical to r7/r8)
__global__ __launch_bounds__(256) void gemm_kernel(
    const __hip_bfloat16* __restrict__ xb, const __hip_bfloat16* __restrict__ Wall,
    const float* __restrict__ bias, __hip_bfloat16* __restrict__ qhead,
    __hip_bfloat16* __restrict__ khead, float* __restrict__ vout) {
  __shared__ __hip_bfloat16 As[128 * 32];
  __shared__ __hip_bfloat16 Bs[128 * 32];
  __shared__ __hip_bfloat16 Cs[128][136];  // +8 pad, rows 16B-aligned
  const int tid = threadIdx.x;
  const int w = tid >> 6, l = tid & 63;
  const int m0 = blockIdx.x * 128;
  const int n0 = blockIdx.y * 128;
  const int wr = w >> 1, wc = w & 1;

  f32x4 acc[4][4] = {};

  const int sr0 = (w * 2 + 0) * 16 + (l >> 2);
  const int sr1 = (w * 2 + 1) * 16 + (l >> 2);
  const int sc = (l & 3) * 8;

  for (int kt = 0; kt < EMB / 32; ++kt) {
    const int k0 = kt * 32;
    gload_lds16(xb + (size_t)(m0 + sr0) * EMB + k0 + sc, (void*)(As + (w * 2 + 0) * 512));
    gload_lds16(xb + (size_t)(m0 + sr1) * EMB + k0 + sc, (void*)(As + (w * 2 + 1) * 512));
    gload_lds16(Wall + (size_t)(n0 + sr0) * EMB + k0 + sc, (void*)(Bs + (w * 2 + 0) * 512));
    gload_lds16(Wall + (size_t)(n0 + sr1) * EMB + k0 + sc, (void*)(Bs + (w * 2 + 1) * 512));
    __syncthreads();

    bf16x8 af[4], bfr[4];
#pragma unroll
    for (int t = 0; t < 4; ++t) {
      af[t] = *reinterpret_cast<const bf16x8*>(As + (wr * 64 + t * 16 + (l & 15)) * 32 + (l >> 4) * 8);
      bfr[t] = *reinterpret_cast<const bf16x8*>(Bs + (wc * 64 + t * 16 + (l & 15)) * 32 + (l >> 4) * 8);
    }
#pragma unroll
    for (int i = 0; i < 4; ++i)
#pragma unroll
      for (int j = 0; j < 4; ++j)
        acc[i][j] = __builtin_amdgcn_mfma_f32_16x16x32_bf16(af[i], bfr[j], acc[i][j], 0, 0, 0);
    __syncthreads();
  }

  if (n0 >= 2 * EMB) {
    const int rowbase = m0 + wr * 64;
    const int colbase = n0 - 2 * EMB + wc * 64;
#pragma unroll
    for (int j = 0; j < 4; ++j) {
      const int n = colbase + j * 16 + (l & 15);
      const float bb = bias[2 * EMB + n];
#pragma unroll
      for (int i = 0; i < 4; ++i) {
#pragma unroll
        for (int q = 0; q < 4; ++q) {
          const int m = rowbase + i * 16 + (l >> 4) * 4 + q;
          vout[(size_t)m * EMB + n] = acc[i][j][q] + bb;
        }
      }
    }
  } else {
#pragma unroll
    for (int j = 0; j < 4; ++j) {
      const int nl = wc * 64 + j * 16 + (l & 15);
      const float bb = bias[n0 + nl];
#pragma unroll
      for (int i = 0; i < 4; ++i) {
#pragma unroll
        for (int q = 0; q < 4; ++q) {
          const int ml = wr * 64 + i * 16 + (l >> 4) * 4 + q;
          Cs[ml][nl] = __float2bfloat16(acc[i][j][q] + bb);
        }
      }
    }
    __syncthreads();
    __hip_bfloat16* dst = (n0 >= EMB) ? khead : qhead;
    const int ch0 = (n0 >= EMB) ? (n0 - EMB) : n0;
    const int cg = (tid & 15) * 8;
    const int gch = ch0 + cg;
    const int hh = gch / DH, dd = gch - hh * DH;
#pragma unroll
    for (int pass = 0; pass < 8; ++pass) {
      const int r = pass * 16 + (tid >> 4);
      const int m = m0 + r;
      const int bb_ = m >> 10, mm = m & 1023;
      bf16x8 v8 = *reinterpret_cast<const bf16x8*>(&Cs[r][cg]);
      *reinterpret_cast<bf16x8*>(dst + ((size_t)(bb_ * NH + hh) * SEQ + mm) * DH + dd) = v8;
    }
  }
}

// ---------------- fused QK^T + softmax: 4-item persistent pipeline ----------------
// Grid 1024 (decode keeps the 8 b-variants sharing rel rows on one XCD), 512 thr,
// 8 waves. Block = 64 q-rows (4 items x 16) x 1024 cols of one (b,h). ONE continuous
// 32-chunk K stream (ring-2 per wave, counted vmcnt, no drain at item boundaries):
// next item's q prefetched at k==6, rel at k==7; stores overlap next item's waits.
// Raw s_barrier + lgkmcnt(0) for softmax reductions (no vmcnt(0) drain).
// vmcnt counts (ops younger than awaited stage, derived exactly):
//   k==0: item0 -> 3, else 22 (= qfn3 + S_next3 + relv8 + st8)
//   k==1: item0 -> 3, else 11 (= st8 + S3) ; k in [2,6] -> 3
//   k==7: last item -> 0, else 6 (= S3 + qfn3)
__global__ __launch_bounds__(512, 4) void attn_kernel(
    const __hip_bfloat16* __restrict__ qhead, const __hip_bfloat16* __restrict__ khead,
    const float* __restrict__ rel, float* __restrict__ eout) {
  __shared__ alignas(16) char KS[8 * 2 * 3072];  // 49152 B: 8 waves x ring-2
  __shared__ float redm[16][8];
  __shared__ float reds[16][8];

  const int t = threadIdx.x;
  const int w = t >> 6, l = t & 63;
  const int lr = l >> 4, lc = l & 15;
  // decode: flat = v*64 + b*8 + x ; g = v*8 + x ; (h, rg) from g -> b-variants same XCD
  const int flat = blockIdx.x;
  const int v = flat >> 6;           // 0..15
  const int b = (flat >> 3) & 7;
  const int g = v * 8 + (flat & 7);  // 0..127
  const int h = g >> 4;              // 0..7
  const int rg = g & 15;             // 0..15 -> rows rg*64 .. +64
  const size_t bh = (size_t)(b * NH + h);

  const __hip_bfloat16* kbh = khead + bh * SEQ * DH;
  char* kdst = KS + w * 6144;

#define STAGE_K(k, buf)                                                            \
  {                                                                                \
    const __hip_bfloat16* s_ = kbh + (size_t)((k) * 128 + w * 16) * DH + l * 8;    \
    gload_lds16(s_, kdst + (buf) * 3072);                                          \
    gload_lds16(s_ + 512, kdst + (buf) * 3072 + 1024);                             \
    gload_lds16(s_ + 1024, kdst + (buf) * 3072 + 2048);                            \
  }

  bf16x8 qfc[3], qfn[3];
  f32x4 relv[8], acc[8];

  // ---- item-0 prologue: q + rel + first 2 stages ----
  const __hip_bfloat16* qsrc0 = qhead + (bh * SEQ + rg * 64 + lc) * DH;
#pragma unroll
  for (int kc = 0; kc < 3; ++kc)
    qfc[kc] = *reinterpret_cast<const bf16x8*>(qsrc0 + kc * 32 + lr * 8);
  const float* relbase = rel + ((size_t)h * SEQ + rg * 64 + lc) * SEQ + w * 16 + lr * 4;
#pragma unroll
  for (int k = 0; k < 8; ++k)
    relv[k] = *reinterpret_cast<const f32x4*>(relbase + k * 128);
  STAGE_K(0, 0)
  STAGE_K(1, 1)

  for (int item = 0; item < 4; ++item) {
    const int row0 = rg * 64 + item * 16;
#pragma unroll
    for (int k = 0; k < 8; ++k) {
      // ---- counted wait for this chunk's staging ----
      if (k == 0) {
        if (item == 0) { asm volatile("s_waitcnt vmcnt(3)" ::: "memory"); }
        else           { asm volatile("s_waitcnt vmcnt(22)" ::: "memory"); }
      } else if (k == 1) {
        if (item == 0) { asm volatile("s_waitcnt vmcnt(3)" ::: "memory"); }
        else           { asm volatile("s_waitcnt vmcnt(11)" ::: "memory"); }
      } else if (k == 7) {
        if (item == 3) { asm volatile("s_waitcnt vmcnt(0)" ::: "memory"); }
        else           { asm volatile("s_waitcnt vmcnt(6)" ::: "memory"); }
      } else {
        asm volatile("s_waitcnt vmcnt(3)" ::: "memory");
      }
      __builtin_amdgcn_sched_barrier(0);

      // ---- LDS -> K fragments ----
      const char* kp = kdst + (k & 1) * 3072 + lc * 192;
      bf16x8 kf[3];
#pragma unroll
      for (int kc = 0; kc < 3; ++kc)
        kf[kc] = *reinterpret_cast<const bf16x8*>(kp + kc * 64 + lr * 16);
      asm volatile("s_waitcnt lgkmcnt(0)" ::: "memory");  // kf in regs; buffer free
      __builtin_amdgcn_sched_barrier(0);

      // ---- re-stage freed buffer (chunk c+2 of the continuous stream) ----
      if (k <= 5) {
        STAGE_K(k + 2, k & 1)
      } else if (k == 6) {
        if (item < 3) {
          STAGE_K(0, 0)  // next item's chunk 0
          __builtin_amdgcn_sched_barrier(0);
          // next item's Q under this item's tail
          const __hip_bfloat16* qn = qhead + (bh * SEQ + row0 + 16 + lc) * DH;
#pragma unroll
          for (int kc = 0; kc < 3; ++kc)
            qfn[kc] = *reinterpret_cast<const bf16x8*>(qn + kc * 32 + lr * 8);
        }
      } else {  // k == 7
        if (item < 3) STAGE_K(1, 1)
      }

      // ---- MFMA + rel add ----
      __builtin_amdgcn_s_setprio(1);
      f32x4 a = {0.f, 0.f, 0.f, 0.f};
#pragma unroll
      for (int kc = 0; kc < 3; ++kc)
        a = __builtin_amdgcn_mfma_f32_16x16x32_bf16(kf[kc], qfc[kc], a, 0, 0, 0);
      __builtin_amdgcn_s_setprio(0);
      acc[k] = a + relv[k];

      // ---- next item's rel (after last use of relv[7]) ----
      if (k == 7 && item < 3) {
        const float* rn = relbase + (size_t)(item + 1) * 16 * SEQ;
#pragma unroll
        for (int kk = 0; kk < 8; ++kk)
          relv[kk] = *reinterpret_cast<const f32x4*>(rn + kk * 128);
      }
    }

    // ---- softmax (raw barriers: lgkmcnt only, vmcnt stays counted) ----
    float mx = -3.4e38f;
#pragma unroll
    for (int k = 0; k < 8; ++k)
      mx = fmaxf(mx, fmaxf(fmaxf(acc[k][0], acc[k][1]), fmaxf(acc[k][2], acc[k][3])));
    mx = fmaxf(mx, __shfl_xor(mx, 16));
    mx = fmaxf(mx, __shfl_xor(mx, 32));
    if (l < 16) redm[lc][w] = mx;
    asm volatile("s_waitcnt lgkmcnt(0)" ::: "memory");
    __builtin_amdgcn_s_barrier();
    asm volatile("" ::: "memory");
    float M = redm[lc][0];
#pragma unroll
    for (int i = 1; i < 8; ++i) M = fmaxf(M, redm[lc][i]);

    float sm = 0.f;
#pragma unroll
    for (int k = 0; k < 8; ++k) {
#pragma unroll
      for (int j = 0; j < 4; ++j) {
        float e = __expf(acc[k][j] - M);
        acc[k][j] = e;
        sm += e;
      }
    }
    sm += __shfl_xor(sm, 16);
    sm += __shfl_xor(sm, 32);
    if (l < 16) reds[lc][w] = sm;
    asm volatile("s_waitcnt lgkmcnt(0)" ::: "memory");
    __builtin_amdgcn_s_barrier();
    asm volatile("" ::: "memory");
    float S = 0.f;
#pragma unroll
    for (int i = 0; i < 8; ++i) S += reds[lc][i];
    const float rinv = 1.0f / S;

    // ---- stores (overlap next item's chunk waits; counted as 8 vmem ops) ----
    float* op = eout + (bh * SEQ + row0 + lc) * SEQ + w * 16 + lr * 4;
#pragma unroll
    for (int k = 0; k < 8; ++k) {
      f32x4 vv = acc[k] * rinv;
      *reinterpret_cast<f32x4*>(op + k * 128) = vv;
    }

    if (item < 3) {
#pragma unroll
      for (int kc = 0; kc < 3; ++kc) qfc[kc] = qfn[kc];
    }
  }
#undef STAGE_K
}

extern "C" void kernel_launch(void* const* d_in, const int* in_sizes, int n_in,
                              void* d_out, int out_size, void* d_ws, size_t ws_size,
                              hipStream_t stream) {
  const float* x = (const float*)d_in[0];
  const float* rel = (const float*)d_in[1];
  const float* qkv_w = (const float*)d_in[2];
  const float* qkv_b = (const float*)d_in[3];
  const float* val_w = (const float*)d_in[4];
  const float* val_b = (const float*)d_in[5];
  float* out = (float*)d_out;

  char* ws = (char*)d_ws;
  __hip_bfloat16* xb = (__hip_bfloat16*)(ws);                  // 12,582,912
  __hip_bfloat16* Wall = (__hip_bfloat16*)(ws + 12582912);     //  3,538,944
  float* bias = (float*)(ws + 16121856);                       //      9,216
  __hip_bfloat16* qhead = (__hip_bfloat16*)(ws + 16131072);    // 12,582,912  [b][h][n][96]
  __hip_bfloat16* khead = (__hip_bfloat16*)(ws + 28713984);    // 12,582,912  [b][h][n][96]

  float* vout = out;                       // [8192][768] values
  float* eout = out + (size_t)M_TOT * EMB; // [64][1024][1024] energy

  prep_x_kernel<<<dim3(M_TOT * EMB / 4 / 256), dim3(256), 0, stream>>>(x, xb);
  prep_w_kernel<<<dim3(NCOLS * EMB / 256), dim3(256), 0, stream>>>(qkv_w, qkv_b, val_w, val_b,
                                                                   Wall, bias);
  gemm_kernel<<<dim3(M_TOT / 128, NCOLS / 128), dim3(256), 0, stream>>>(xb, Wall, bias, qhead,
                                                                        khead, vout);
  attn_kernel<<<dim3(SEQ / 64 * NH * BATCH), dim3(512), 0, stream>>>(qhead, khead, rel, eout);
}

// Round 11
// 161.146 us; speedup vs baseline: 1.6506x; 1.6506x over previous
//
#include <hip/hip_runtime.h>
#include <hip/hip_bf16.h>

#define EMB 768
#define NH 8
#define DH 96
#define BATCH 8
#define SEQ 1024
#define M_TOT (BATCH * SEQ)   // 8192 rows of x
#define NCOLS (3 * EMB)       // q(768) | k(768) | v(768) output channels

typedef float f32x4 __attribute__((ext_vector_type(4)));
typedef __bf16 bf16x8 __attribute__((ext_vector_type(8)));

__device__ __forceinline__ unsigned short f2bf_bits(float f) {
  __hip_bfloat16 b = __float2bfloat16(f);
  return *reinterpret_cast<unsigned short*>(&b);
}

__device__ __forceinline__ void gload_lds16(const void* g, void* l) {
  // async global->LDS, 16B per lane; LDS dest is wave-uniform base (+lane*16 by HW)
  __builtin_amdgcn_global_load_lds(
      (__attribute__((address_space(1))) void*)(g),
      (__attribute__((address_space(3))) void*)(l), 16, 0, 0);
}

// ---------------- prep: x fp32 -> bf16 ----------------
__global__ void prep_x_kernel(const float* __restrict__ x, __hip_bfloat16* __restrict__ xb) {
  const int n4 = M_TOT * EMB / 4;
  int i = blockIdx.x * blockDim.x + threadIdx.x;
  if (i < n4) {
    f32x4 v = reinterpret_cast<const f32x4*>(x)[i];
    ushort4 o;
    o.x = f2bf_bits(v[0]);
    o.y = f2bf_bits(v[1]);
    o.z = f2bf_bits(v[2]);
    o.w = f2bf_bits(v[3]);
    reinterpret_cast<ushort4*>(xb)[i] = o;
  }
}

// ---------------- prep: permuted weights -> bf16, bias fp32 ----------------
__global__ void prep_w_kernel(const float* __restrict__ qkv_w, const float* __restrict__ qkv_b,
                              const float* __restrict__ val_w, const float* __restrict__ val_b,
                              __hip_bfloat16* __restrict__ Wall, float* __restrict__ bias) {
  const float inv_s = 0.03608439182435161f;  // 1/sqrt(768)
  int idx = blockIdx.x * 256 + threadIdx.x;
  if (idx >= NCOLS * EMB) return;
  int r = idx / EMB;
  int c = idx - r * EMB;
  float v;
  if (r < EMB) {
    int h = r / DH, d = r - h * DH;
    int src = h * 192 + 2 * d;
    v = qkv_w[(size_t)src * EMB + c] * inv_s;
    if (c == 0) bias[r] = qkv_b[src] * inv_s;
  } else if (r < 2 * EMB) {
    int r2 = r - EMB;
    int h = r2 / DH, d = r2 - h * DH;
    int src = h * 192 + 2 * d + 1;
    v = qkv_w[(size_t)src * EMB + c];
    if (c == 0) bias[r] = qkv_b[src];
  } else {
    int r3 = r - 2 * EMB;
    v = val_w[(size_t)r3 * EMB + c];
    if (c == 0) bias[r] = val_b[r3];
  }
  Wall[idx] = __float2bfloat16(v);
}

// ---------------- fused projection GEMM (m97-structure, 128x128, BK=32) ----------------
// q/k tiles: acc -> LDS (bf16) -> cooperative coalesced store into head-packed
// [b][h][n][96] layout. v tile: direct fp32 stores.  (byte-identical to r7/r8)
__global__ __launch_bounds__(256) void gemm_kernel(
    const __hip_bfloat16* __restrict__ xb, const __hip_bfloat16* __restrict__ Wall,
    const float* __restrict__ bias, __hip_bfloat16* __restrict__ qhead,
    __hip_bfloat16* __restrict__ khead, float* __restrict__ vout) {
  __shared__ __hip_bfloat16 As[128 * 32];
  __shared__ __hip_bfloat16 Bs[128 * 32];
  __shared__ __hip_bfloat16 Cs[128][136];  // +8 pad, rows 16B-aligned
  const int tid = threadIdx.x;
  const int w = tid >> 6, l = tid & 63;
  const int m0 = blockIdx.x * 128;
  const int n0 = blockIdx.y * 128;
  const int wr = w >> 1, wc = w & 1;

  f32x4 acc[4][4] = {};

  const int sr0 = (w * 2 + 0) * 16 + (l >> 2);
  const int sr1 = (w * 2 + 1) * 16 + (l >> 2);
  const int sc = (l & 3) * 8;

  for (int kt = 0; kt < EMB / 32; ++kt) {
    const int k0 = kt * 32;
    gload_lds16(xb + (size_t)(m0 + sr0) * EMB + k0 + sc, (void*)(As + (w * 2 + 0) * 512));
    gload_lds16(xb + (size_t)(m0 + sr1) * EMB + k0 + sc, (void*)(As + (w * 2 + 1) * 512));
    gload_lds16(Wall + (size_t)(n0 + sr0) * EMB + k0 + sc, (void*)(Bs + (w * 2 + 0) * 512));
    gload_lds16(Wall + (size_t)(n0 + sr1) * EMB + k0 + sc, (void*)(Bs + (w * 2 + 1) * 512));
    __syncthreads();

    bf16x8 af[4], bfr[4];
#pragma unroll
    for (int t = 0; t < 4; ++t) {
      af[t] = *reinterpret_cast<const bf16x8*>(As + (wr * 64 + t * 16 + (l & 15)) * 32 + (l >> 4) * 8);
      bfr[t] = *reinterpret_cast<const bf16x8*>(Bs + (wc * 64 + t * 16 + (l & 15)) * 32 + (l >> 4) * 8);
    }
#pragma unroll
    for (int i = 0; i < 4; ++i)
#pragma unroll
      for (int j = 0; j < 4; ++j)
        acc[i][j] = __builtin_amdgcn_mfma_f32_16x16x32_bf16(af[i], bfr[j], acc[i][j], 0, 0, 0);
    __syncthreads();
  }

  if (n0 >= 2 * EMB) {
    const int rowbase = m0 + wr * 64;
    const int colbase = n0 - 2 * EMB + wc * 64;
#pragma unroll
    for (int j = 0; j < 4; ++j) {
      const int n = colbase + j * 16 + (l & 15);
      const float bb = bias[2 * EMB + n];
#pragma unroll
      for (int i = 0; i < 4; ++i) {
#pragma unroll
        for (int q = 0; q < 4; ++q) {
          const int m = rowbase + i * 16 + (l >> 4) * 4 + q;
          vout[(size_t)m * EMB + n] = acc[i][j][q] + bb;
        }
      }
    }
  } else {
#pragma unroll
    for (int j = 0; j < 4; ++j) {
      const int nl = wc * 64 + j * 16 + (l & 15);
      const float bb = bias[n0 + nl];
#pragma unroll
      for (int i = 0; i < 4; ++i) {
#pragma unroll
        for (int q = 0; q < 4; ++q) {
          const int ml = wr * 64 + i * 16 + (l >> 4) * 4 + q;
          Cs[ml][nl] = __float2bfloat16(acc[i][j][q] + bb);
        }
      }
    }
    __syncthreads();
    __hip_bfloat16* dst = (n0 >= EMB) ? khead : qhead;
    const int ch0 = (n0 >= EMB) ? (n0 - EMB) : n0;
    const int cg = (tid & 15) * 8;
    const int gch = ch0 + cg;
    const int hh = gch / DH, dd = gch - hh * DH;
#pragma unroll
    for (int pass = 0; pass < 8; ++pass) {
      const int r = pass * 16 + (tid >> 4);
      const int m = m0 + r;
      const int bb_ = m >> 10, mm = m & 1023;
      bf16x8 v8 = *reinterpret_cast<const bf16x8*>(&Cs[r][cg]);
      *reinterpret_cast<bf16x8*>(dst + ((size_t)(bb_ * NH + hh) * SEQ + mm) * DH + dd) = v8;
    }
  }
}

// ---------------- fused QK^T + softmax: r7 structure + wave-contiguous cols + nt stores ----
// Grid 4096 (decode keeps the 8 b-variants sharing rel rows on one XCD: flat%8 fixed
// across b). 512 thr = 8 waves; block = 16 q-rows x 1024 k-cols. Wave w owns the
// CONTIGUOUS col range [w*128, w*128+128) -> its 8 stores per row form one 512B run
// (full 128B-line merging, no cross-wave split lines). Energy stored NON-TEMPORAL:
// write-once data bypasses L2/L3 retention, preserving rel/K reuse (fix for r10's
// 364MB FETCH / 378MB WRITE thrash). K staged per-wave (16-row chunks, contiguous
// 3KB), ring-3, counted vmcnt(6/3/0) -- no __syncthreads in the K loop.
__global__ __launch_bounds__(512, 2) void attn_kernel(
    const __hip_bfloat16* __restrict__ qhead, const __hip_bfloat16* __restrict__ khead,
    const float* __restrict__ rel, float* __restrict__ eout) {
  __shared__ alignas(16) char KS[8 * 3 * 3072];  // 73728 B: 8 waves x ring of 3
  __shared__ float redm[16][8];
  __shared__ float reds[16][8];

  const int t = threadIdx.x;
  const int w = t >> 6, l = t & 63;
  const int lr = l >> 4, lc = l & 15;
  // decode: flat = u*64 + b*8 + x ; g = u*8 + x -> b-variants 8 apart = same XCD
  const int flat = blockIdx.x;
  const int u = flat >> 6;
  const int b = (flat >> 3) & 7;
  const int g = u * 8 + (flat & 7);
  const int h = g >> 6;
  const int rb = g & 63;
  const int row0 = rb * 16;
  const size_t bh = (size_t)(b * NH + h);

  // ---- Q fragments direct from head-packed global ----
  const __hip_bfloat16* qsrc = qhead + (bh * SEQ + row0 + lc) * DH;
  bf16x8 qf[3];
#pragma unroll
  for (int kc = 0; kc < 3; ++kc)
    qf[kc] = *reinterpret_cast<const bf16x8*>(qsrc + kc * 32 + lr * 8);

  // ---- all rel loads hoisted (wave-contiguous col range) ----
  const float* relsrc = rel + ((size_t)h * SEQ + row0 + lc) * SEQ + w * 128 + lr * 4;
  f32x4 relv[8];
#pragma unroll
  for (int s = 0; s < 8; ++s)
    relv[s] = *reinterpret_cast<const f32x4*>(relsrc + s * 16);

  // ---- per-wave K staging: rows [w*128, w*128+128), 16-row chunks of 3KB ----
  const __hip_bfloat16* ksrc = khead + bh * SEQ * DH + (size_t)w * 128 * DH;
  char* kdst = KS + w * 9216;

#define STAGE_K(s, buf)                                                             \
  {                                                                                 \
    const __hip_bfloat16* s_ = ksrc + (size_t)(s) * 1536 + (size_t)l * 8;           \
    gload_lds16(s_, kdst + (buf) * 3072);                                           \
    gload_lds16(s_ + 512, kdst + (buf) * 3072 + 1024);                              \
    gload_lds16(s_ + 1024, kdst + (buf) * 3072 + 2048);                             \
  }

  STAGE_K(0, 0)
  STAGE_K(1, 1)

  f32x4 acc[8];
#pragma unroll
  for (int s = 0; s < 8; ++s) {
    if (s < 6) STAGE_K(s + 2, (s + 2) % 3)
    if (s < 6) {
      asm volatile("s_waitcnt vmcnt(6)" ::: "memory");
    } else if (s == 6) {
      asm volatile("s_waitcnt vmcnt(3)" ::: "memory");
    } else {
      asm volatile("s_waitcnt vmcnt(0)" ::: "memory");
    }
    __builtin_amdgcn_sched_barrier(0);
    const __hip_bfloat16* kp =
        reinterpret_cast<const __hip_bfloat16*>(kdst + (s % 3) * 3072) + lc * DH;
    f32x4 a = {0.f, 0.f, 0.f, 0.f};
    __builtin_amdgcn_s_setprio(1);
#pragma unroll
    for (int kc = 0; kc < 3; ++kc) {
      bf16x8 kf = *reinterpret_cast<const bf16x8*>(kp + kc * 32 + lr * 8);
      a = __builtin_amdgcn_mfma_f32_16x16x32_bf16(kf, qf[kc], a, 0, 0, 0);
    }
    __builtin_amdgcn_s_setprio(0);
    acc[s] = a + relv[s];
  }
#undef STAGE_K

  // ---- softmax (score: q-row = row0+lc, k-col = w*128 + s*16 + lr*4 + j) ----
  float mx = -3.4e38f;
#pragma unroll
  for (int s = 0; s < 8; ++s)
    mx = fmaxf(mx, fmaxf(fmaxf(acc[s][0], acc[s][1]), fmaxf(acc[s][2], acc[s][3])));
  mx = fmaxf(mx, __shfl_xor(mx, 16));
  mx = fmaxf(mx, __shfl_xor(mx, 32));
  if (l < 16) redm[lc][w] = mx;
  __syncthreads();
  float M = redm[lc][0];
#pragma unroll
  for (int i = 1; i < 8; ++i) M = fmaxf(M, redm[lc][i]);

  float sm = 0.f;
#pragma unroll
  for (int s = 0; s < 8; ++s) {
#pragma unroll
    for (int j = 0; j < 4; ++j) {
      float e = __expf(acc[s][j] - M);
      acc[s][j] = e;
      sm += e;
    }
  }
  sm += __shfl_xor(sm, 16);
  sm += __shfl_xor(sm, 32);
  if (l < 16) reds[lc][w] = sm;
  __syncthreads();
  float S = 0.f;
#pragma unroll
  for (int i = 0; i < 8; ++i) S += reds[lc][i];
  const float rinv = 1.0f / S;

  // ---- non-temporal stores: per wave-row a contiguous 512B run (s=0..7 x 64B) ----
  float* op = eout + (bh * SEQ + row0 + lc) * SEQ + w * 128 + lr * 4;
#pragma unroll
  for (int s = 0; s < 8; ++s) {
    f32x4 v = acc[s] * rinv;
    __builtin_nontemporal_store(v, reinterpret_cast<f32x4*>(op + s * 16));
  }
}

extern "C" void kernel_launch(void* const* d_in, const int* in_sizes, int n_in,
                              void* d_out, int out_size, void* d_ws, size_t ws_size,
                              hipStream_t stream) {
  const float* x = (const float*)d_in[0];
  const float* rel = (const float*)d_in[1];
  const float* qkv_w = (const float*)d_in[2];
  const float* qkv_b = (const float*)d_in[3];
  const float* val_w = (const float*)d_in[4];
  const float* val_b = (const float*)d_in[5];
  float* out = (float*)d_out;

  char* ws = (char*)d_ws;
  __hip_bfloat16* xb = (__hip_bfloat16*)(ws);                  // 12,582,912
  __hip_bfloat16* Wall = (__hip_bfloat16*)(ws + 12582912);     //  3,538,944
  float* bias = (float*)(ws + 16121856);                       //      9,216
  __hip_bfloat16* qhead = (__hip_bfloat16*)(ws + 16131072);    // 12,582,912  [b][h][n][96]
  __hip_bfloat16* khead = (__hip_bfloat16*)(ws + 28713984);    // 12,582,912  [b][h][n][96]

  float* vout = out;                       // [8192][768] values
  float* eout = out + (size_t)M_TOT * EMB; // [64][1024][1024] energy

  prep_x_kernel<<<dim3(M_TOT * EMB / 4 / 256), dim3(256), 0, stream>>>(x, xb);
  prep_w_kernel<<<dim3(NCOLS * EMB / 256), dim3(256), 0, stream>>>(qkv_w, qkv_b, val_w, val_b,
                                                                   Wall, bias);
  gemm_kernel<<<dim3(M_TOT / 128, NCOLS / 128), dim3(256), 0, stream>>>(xb, Wall, bias, qhead,
                                                                        khead, vout);
  attn_kernel<<<dim3(SEQ / 16 * NH * BATCH), dim3(512), 0, stream>>>(qhead, khead, rel, eout);
}